// Round 1
// baseline (834.157 us; speedup 1.0000x reference)
//
#include <hip/hip_runtime.h>
#include <hip/hip_bf16.h>
#include <math.h>

#define NATOMS 16384
#define NEDGE  524288
#define NINT   6
#define NGAUSS 50
#define TK     8192
#define INV_DT 512.0f    // knots at d = k/512, range [0,16)
#define DT     (1.0f/512.0f)
#define LOG2F_ 0.69314718055994530942f

__device__ __forceinline__ float sspf(float v){
    // softplus(v) - log(2), numerically stable
    return fmaxf(v, 0.f) + log1pf(__expf(-fabsf(v))) - LOG2F_;
}

// ---------------- h = emb[z]  (both graphs concatenated: rows 0..N-1 = A, N..2N-1 = G)
__global__ __launch_bounds__(256) void k_embed(const int* __restrict__ zA, const int* __restrict__ zG,
                                               const float* __restrict__ emb, float* __restrict__ h){
    int idx = blockIdx.x * 256 + threadIdx.x;        // < 2*NATOMS*64
    int n = idx >> 6, f = idx & 63;
    int z = (n < NATOMS) ? zA[n] : zG[n - NATOMS];
    h[idx] = emb[(z << 6) + f];
}

// ---------------- histogram of dst per graph
__global__ __launch_bounds__(256) void k_hist(const int* __restrict__ edgeA, const int* __restrict__ edgeG,
                                              int* __restrict__ hist){
    int e = blockIdx.x * 256 + threadIdx.x;          // < 2*NEDGE
    int g = e >= NEDGE;
    int el = e - (g ? NEDGE : 0);
    const int* edge = g ? edgeG : edgeA;
    atomicAdd(&hist[g * NATOMS + edge[NEDGE + el]], 1);
}

// ---------------- exclusive scan (one block of 1024 per graph) -> rowptr + cursor
__global__ __launch_bounds__(1024) void k_scan(const int* __restrict__ hist, int* __restrict__ rowptr,
                                               int* __restrict__ cursor){
    int g = blockIdx.x;
    const int* hg = hist + g * NATOMS;
    int* rp = rowptr + g * (NATOMS + 1);
    int* cu = cursor + g * NATOMS;
    __shared__ int ssum[1024];
    int t = threadIdx.x;
    int base = t * 16;
    int v[16]; int s = 0;
    #pragma unroll
    for (int j = 0; j < 16; j++){ v[j] = hg[base + j]; s += v[j]; }
    ssum[t] = s;
    __syncthreads();
    for (int off = 1; off < 1024; off <<= 1){
        int add = (t >= off) ? ssum[t - off] : 0;
        __syncthreads();
        ssum[t] += add;
        __syncthreads();
    }
    int run = ssum[t] - s;   // exclusive prefix of this thread's chunk
    #pragma unroll
    for (int j = 0; j < 16; j++){ rp[base + j] = run; cu[base + j] = run; run += v[j]; }
    if (t == 1023) rp[NATOMS] = ssum[1023];
}

// ---------------- compute per-edge geometry, place into dst-sorted meta array
__global__ __launch_bounds__(256) void k_place(const int* __restrict__ edgeA, const int* __restrict__ edgeG,
                                               const float* __restrict__ posA, const float* __restrict__ posG,
                                               int* __restrict__ cursor, int4* __restrict__ meta){
    int e = blockIdx.x * 256 + threadIdx.x;          // < 2*NEDGE
    int g = e >= NEDGE;
    int el = e - (g ? NEDGE : 0);
    const int* edge = g ? edgeG : edgeA;
    const float* pos = g ? posG : posA;
    int src = edge[el], dst = edge[NEDGE + el];
    float dx = pos[src*3+0] - pos[dst*3+0];
    float dy = pos[src*3+1] - pos[dst*3+1];
    float dz = pos[src*3+2] - pos[dst*3+2];
    float d  = sqrtf(fmaf(dx,dx, fmaf(dy,dy, fmaf(dz,dz, 1e-12f))));
    float cc = 0.5f * (__cosf(d * 0.31415926535897932f) + 1.0f);  // cosine cutoff, formula for all d
    float tp = d * INV_DT;
    int   ti = (int)tp; if (ti > TK - 2) ti = TK - 2;
    float tf = tp - (float)ti;
    int p = atomicAdd(&cursor[g * NATOMS + dst], 1);
    int4 m; m.x = src; m.y = ti; m.z = __float_as_int(tf); m.w = __float_as_int(cc);
    meta[(size_t)g * NEDGE + p] = m;
}

// ---------------- tabulate W_i(d) on TK knots, one wave per (interaction, knot)
__global__ __launch_bounds__(256) void k_tables(const float* __restrict__ mw1, const float* __restrict__ mb1,
                                                const float* __restrict__ mw2, const float* __restrict__ mb2,
                                                float* __restrict__ tab){
    int wv   = blockIdx.x * 4 + (threadIdx.x >> 6);  // < NINT*TK
    int lane = threadIdx.x & 63;
    int i = wv >> 13, k = wv & (TK - 1);
    float d = (float)k * DT;
    const float step  = 10.0f / 49.0f;               // jnp.linspace(0,10,50) spacing
    const float coeff = -0.5f / (step * step);
    float u = mb1[(i << 6) + lane];
    #pragma unroll
    for (int gg = 0; gg < NGAUSS; gg++){
        float od = d - (float)gg * step;
        float ea = __expf(coeff * od * od);
        u = fmaf(ea, mw1[((i * NGAUSS + gg) << 6) + lane], u);
    }
    float t = sspf(u);
    float w = mb2[(i << 6) + lane];
    #pragma unroll
    for (int gg = 0; gg < 64; gg++){
        float tg = __shfl(t, gg, 64);
        w = fmaf(tg, mw2[(((i << 6) + gg) << 6) + lane], w);
    }
    tab[((size_t)(i * TK + k) << 6) + lane] = w;
}

// ---------------- x = h @ l1w (no bias), 64 nodes per block
__global__ __launch_bounds__(256) void k_lin1(const float* __restrict__ h, const float* __restrict__ w,
                                              float* __restrict__ x){
    __shared__ float hs[64 * 64];
    __shared__ float ws_[64 * 64];
    int t = threadIdx.x;
    size_t base = (size_t)blockIdx.x * 64;
    #pragma unroll
    for (int j = 0; j < 16; j++){
        int idx = t + j * 256;
        hs[idx]  = h[base * 64 + idx];
        ws_[idx] = w[idx];
    }
    __syncthreads();
    int te = t >> 4, tf4 = (t & 15) << 2;
    float acc[4][4];
    #pragma unroll
    for (int j = 0; j < 4; j++){ acc[j][0]=0.f; acc[j][1]=0.f; acc[j][2]=0.f; acc[j][3]=0.f; }
    for (int k = 0; k < 64; k++){
        float4 wv = *(const float4*)&ws_[(k << 6) + tf4];
        #pragma unroll
        for (int j = 0; j < 4; j++){
            float hv = hs[((te << 2) + j) * 64 + k];
            acc[j][0] = fmaf(hv, wv.x, acc[j][0]);
            acc[j][1] = fmaf(hv, wv.y, acc[j][1]);
            acc[j][2] = fmaf(hv, wv.z, acc[j][2]);
            acc[j][3] = fmaf(hv, wv.w, acc[j][3]);
        }
    }
    #pragma unroll
    for (int j = 0; j < 4; j++){
        float4 o; o.x=acc[j][0]; o.y=acc[j][1]; o.z=acc[j][2]; o.w=acc[j][3];
        *(float4*)&x[(base + (te << 2) + j) * 64 + tf4] = o;
    }
}

// ---------------- agg[dst] = sum_{edges->dst} x[src] * lerp(tab,d) * C   (one wave per dst atom)
__global__ __launch_bounds__(256) void k_agg(const float* __restrict__ x, const float* __restrict__ tab_i,
                                             const int4* __restrict__ meta, const int* __restrict__ rowptr,
                                             float* __restrict__ agg){
    int wv   = blockIdx.x * 4 + (threadIdx.x >> 6);  // < 2*NATOMS
    int lane = threadIdx.x & 63;
    int g  = wv >= NATOMS;
    int nn = wv - (g ? NATOMS : 0);
    const int* rp = rowptr + g * (NATOMS + 1);
    int lo = rp[nn], hi = rp[nn + 1];
    const int4*  mg = meta + (size_t)g * NEDGE;
    const float* xg = x + ((size_t)(g ? NATOMS : 0) << 6);
    float acc0 = 0.f, acc1 = 0.f;
    int e = lo;
    for (; e + 2 <= hi; e += 2){
        int4 m0 = mg[e], m1 = mg[e + 1];
        float x0 = xg[((size_t)m0.x << 6) + lane];
        float x1 = xg[((size_t)m1.x << 6) + lane];
        const float* t0p = tab_i + ((size_t)m0.y << 6);
        const float* t1p = tab_i + ((size_t)m1.y << 6);
        float a0 = t0p[lane], b0 = t0p[64 + lane];
        float a1 = t1p[lane], b1 = t1p[64 + lane];
        float w0 = fmaf(b0 - a0, __int_as_float(m0.z), a0) * __int_as_float(m0.w);
        float w1 = fmaf(b1 - a1, __int_as_float(m1.z), a1) * __int_as_float(m1.w);
        acc0 = fmaf(w0, x0, acc0);
        acc1 = fmaf(w1, x1, acc1);
    }
    if (e < hi){
        int4 m0 = mg[e];
        float x0 = xg[((size_t)m0.x << 6) + lane];
        const float* t0p = tab_i + ((size_t)m0.y << 6);
        float a0 = t0p[lane], b0 = t0p[64 + lane];
        float w0 = fmaf(b0 - a0, __int_as_float(m0.z), a0) * __int_as_float(m0.w);
        acc0 = fmaf(w0, x0, acc0);
    }
    agg[((size_t)wv << 6) + lane] = acc0 + acc1;
}

// ---------------- h += ssp(agg @ l2w + b2) @ l3w + b3, 64 nodes per block
__global__ __launch_bounds__(256) void k_update(const float* __restrict__ agg, const float* __restrict__ w2,
                                                const float* __restrict__ b2, const float* __restrict__ w3,
                                                const float* __restrict__ b3, float* __restrict__ h){
    __shared__ float as_[64 * 64];
    __shared__ float ts_[64 * 64];
    __shared__ float ws_[64 * 64];
    int t = threadIdx.x;
    size_t base = (size_t)blockIdx.x * 64;
    #pragma unroll
    for (int j = 0; j < 16; j++){
        int idx = t + j * 256;
        as_[idx] = agg[base * 64 + idx];
        ws_[idx] = w2[idx];
    }
    __syncthreads();
    int te = t >> 4, tf4 = (t & 15) << 2;
    float acc[4][4];
    #pragma unroll
    for (int j = 0; j < 4; j++){ acc[j][0]=0.f; acc[j][1]=0.f; acc[j][2]=0.f; acc[j][3]=0.f; }
    for (int k = 0; k < 64; k++){
        float4 wv = *(const float4*)&ws_[(k << 6) + tf4];
        #pragma unroll
        for (int j = 0; j < 4; j++){
            float av = as_[((te << 2) + j) * 64 + k];
            acc[j][0] = fmaf(av, wv.x, acc[j][0]);
            acc[j][1] = fmaf(av, wv.y, acc[j][1]);
            acc[j][2] = fmaf(av, wv.z, acc[j][2]);
            acc[j][3] = fmaf(av, wv.w, acc[j][3]);
        }
    }
    float4 b2v = *(const float4*)&b2[tf4];
    #pragma unroll
    for (int j = 0; j < 4; j++){
        ts_[((te << 2) + j) * 64 + tf4 + 0] = sspf(acc[j][0] + b2v.x);
        ts_[((te << 2) + j) * 64 + tf4 + 1] = sspf(acc[j][1] + b2v.y);
        ts_[((te << 2) + j) * 64 + tf4 + 2] = sspf(acc[j][2] + b2v.z);
        ts_[((te << 2) + j) * 64 + tf4 + 3] = sspf(acc[j][3] + b2v.w);
    }
    __syncthreads();
    #pragma unroll
    for (int j = 0; j < 16; j++){
        int idx = t + j * 256;
        ws_[idx] = w3[idx];
    }
    __syncthreads();
    float ac2[4][4];
    #pragma unroll
    for (int j = 0; j < 4; j++){ ac2[j][0]=0.f; ac2[j][1]=0.f; ac2[j][2]=0.f; ac2[j][3]=0.f; }
    for (int k = 0; k < 64; k++){
        float4 wv = *(const float4*)&ws_[(k << 6) + tf4];
        #pragma unroll
        for (int j = 0; j < 4; j++){
            float tv = ts_[((te << 2) + j) * 64 + k];
            ac2[j][0] = fmaf(tv, wv.x, ac2[j][0]);
            ac2[j][1] = fmaf(tv, wv.y, ac2[j][1]);
            ac2[j][2] = fmaf(tv, wv.z, ac2[j][2]);
            ac2[j][3] = fmaf(tv, wv.w, ac2[j][3]);
        }
    }
    float4 b3v = *(const float4*)&b3[tf4];
    #pragma unroll
    for (int j = 0; j < 4; j++){
        size_t o = (base + (te << 2) + j) * 64 + tf4;
        float4 hv = *(float4*)&h[o];
        hv.x += ac2[j][0] + b3v.x;
        hv.y += ac2[j][1] + b3v.y;
        hv.z += ac2[j][2] + b3v.z;
        hv.w += ac2[j][3] + b3v.w;
        *(float4*)&h[o] = hv;
    }
}

// ---------------- readout: eout[g][f] = sum_n h[n][f]  (scaled by 1/256 later)
__global__ __launch_bounds__(256) void k_readout(const float* __restrict__ h, float* __restrict__ eout){
    int f  = threadIdx.x & 63;
    int wq = threadIdx.x >> 6;
    int nodeBase = blockIdx.x * 256 + wq * 64;
    float acc = 0.f;
    #pragma unroll 4
    for (int j = 0; j < 64; j++) acc += h[(size_t)(nodeBase + j) * 64 + f];
    int g = nodeBase >= NATOMS;
    atomicAdd(&eout[g * 64 + f], acc);
}

// ---------------- head: fc1 -> PReLU -> fc2 -> exp
__global__ __launch_bounds__(64) void k_final(const float* __restrict__ eout, const float* __restrict__ addf,
                                              const float* __restrict__ fc1w, const float* __restrict__ fc1b,
                                              const float* __restrict__ pra, const float* __restrict__ fc2w,
                                              const float* __restrict__ fc2b, float* __restrict__ out){
    int f = threadIdx.x;
    float xv = fc1b[f];
    const float inv = 1.0f / 256.0f;
    for (int k = 0; k < 64; k++)  xv = fmaf(eout[k] * inv,      fc1w[k * 64 + f],        xv);
    for (int k = 0; k < 64; k++)  xv = fmaf(eout[64 + k] * inv, fc1w[(64 + k) * 64 + f], xv);
    xv = fmaf(addf[0], fc1w[128 * 64 + f], xv);
    xv = fmaf(addf[1], fc1w[129 * 64 + f], xv);
    float a = pra[0];
    xv = (xv >= 0.f) ? xv : a * xv;
    float s = xv * fc2w[f];
    #pragma unroll
    for (int m = 32; m >= 1; m >>= 1) s += __shfl_xor(s, m, 64);
    if (f == 0) out[0] = expf(s + fc2b[0]);
}

extern "C" void kernel_launch(void* const* d_in, const int* in_sizes, int n_in,
                              void* d_out, int out_size, void* d_ws, size_t ws_size,
                              hipStream_t stream){
    const int*   zA    = (const int*)  d_in[0];
    const float* posA  = (const float*)d_in[1];
    const int*   edgeA = (const int*)  d_in[3];
    const int*   zG    = (const int*)  d_in[4];
    const float* posG  = (const float*)d_in[5];
    const int*   edgeG = (const int*)  d_in[7];
    const float* addf  = (const float*)d_in[8];
    const float* emb   = (const float*)d_in[9];
    const float* mw1   = (const float*)d_in[10];
    const float* mb1   = (const float*)d_in[11];
    const float* mw2   = (const float*)d_in[12];
    const float* mb2   = (const float*)d_in[13];
    const float* l1w   = (const float*)d_in[14];
    const float* l2w   = (const float*)d_in[15];
    const float* l2b   = (const float*)d_in[16];
    const float* l3w   = (const float*)d_in[17];
    const float* l3b   = (const float*)d_in[18];
    const float* fc1w  = (const float*)d_in[19];
    const float* fc1b  = (const float*)d_in[20];
    const float* pra   = (const float*)d_in[21];
    const float* fc2w  = (const float*)d_in[22];
    const float* fc2b  = (const float*)d_in[23];
    float* out = (float*)d_out;

    // workspace layout (~55 MB total)
    char* p = (char*)d_ws;
    auto alloc = [&](size_t bytes)->char*{ char* r = p; p += (bytes + 255) & ~(size_t)255; return r; };
    float* tab    = (float*)alloc((size_t)NINT * TK * 64 * 4);        // 12.6 MB
    int4*  meta   = (int4*) alloc((size_t)2 * NEDGE * 16);            // 16.8 MB
    int*   rowptr = (int*)  alloc((size_t)2 * (NATOMS + 1) * 4);
    int*   cursor = (int*)  alloc((size_t)2 * NATOMS * 4);
    int*   hist   = (int*)  alloc((size_t)2 * NATOMS * 4);
    float* h      = (float*)alloc((size_t)2 * NATOMS * 64 * 4);       // 8.4 MB
    float* x      = (float*)alloc((size_t)2 * NATOMS * 64 * 4);       // 8.4 MB
    float* agg    = (float*)alloc((size_t)2 * NATOMS * 64 * 4);       // 8.4 MB
    float* eout   = (float*)alloc(128 * 4);

    hipMemsetAsync(hist, 0, (size_t)2 * NATOMS * 4, stream);
    hipMemsetAsync(eout, 0, 128 * 4, stream);

    k_embed <<<(2 * NATOMS * 64) / 256, 256, 0, stream>>>(zA, zG, emb, h);
    k_hist  <<<(2 * NEDGE) / 256,       256, 0, stream>>>(edgeA, edgeG, hist);
    k_scan  <<<2, 1024, 0, stream>>>(hist, rowptr, cursor);
    k_place <<<(2 * NEDGE) / 256,       256, 0, stream>>>(edgeA, edgeG, posA, posG, cursor, meta);
    k_tables<<<(NINT * TK) / 4,         256, 0, stream>>>(mw1, mb1, mw2, mb2, tab);

    for (int i = 0; i < NINT; i++){
        k_lin1  <<<(2 * NATOMS) / 64, 256, 0, stream>>>(h, l1w + i * 4096, x);
        k_agg   <<<(2 * NATOMS) / 4,  256, 0, stream>>>(x, tab + (size_t)i * TK * 64, meta, rowptr, agg);
        k_update<<<(2 * NATOMS) / 64, 256, 0, stream>>>(agg, l2w + i * 4096, l2b + i * 64,
                                                        l3w + i * 4096, l3b + i * 64, h);
    }

    k_readout<<<(2 * NATOMS) / 256, 256, 0, stream>>>(h, eout);
    k_final  <<<1, 64, 0, stream>>>(eout, addf, fc1w, fc1b, pra, fc2w, fc2b, out);
}

// Round 2
// 682.898 us; speedup vs baseline: 1.2215x; 1.2215x over previous
//
#include <hip/hip_runtime.h>
#include <hip/hip_bf16.h>
#include <hip/hip_fp16.h>
#include <math.h>

#define NATOMS 16384
#define NEDGE  524288
#define NINT   6
#define NGAUSS 50
#define TK     8192
#define INV_DT 512.0f    // knots at d = k/512, range [0,16)
#define DT     (1.0f/512.0f)
#define LOG2F_ 0.69314718055994530942f

__device__ __forceinline__ float sspf(float v){
    // softplus(v) - log(2), numerically stable
    return fmaxf(v, 0.f) + log1pf(__expf(-fabsf(v))) - LOG2F_;
}

// ---------------- h = emb[z]  (rows 0..N-1 = A, N..2N-1 = G)
__global__ __launch_bounds__(256) void k_embed(const int* __restrict__ zA, const int* __restrict__ zG,
                                               const float* __restrict__ emb, float* __restrict__ h){
    int idx = blockIdx.x * 256 + threadIdx.x;        // < 2*NATOMS*64
    int n = idx >> 6, f = idx & 63;
    int z = (n < NATOMS) ? zA[n] : zG[n - NATOMS];
    h[idx] = emb[(z << 6) + f];
}

// ---------------- histogram of dst per graph
__global__ __launch_bounds__(256) void k_hist(const int* __restrict__ edgeA, const int* __restrict__ edgeG,
                                              int* __restrict__ hist){
    int e = blockIdx.x * 256 + threadIdx.x;          // < 2*NEDGE
    int g = e >= NEDGE;
    int el = e - (g ? NEDGE : 0);
    const int* edge = g ? edgeG : edgeA;
    atomicAdd(&hist[g * NATOMS + edge[NEDGE + el]], 1);
}

// ---------------- exclusive scan (one block of 1024 per graph) -> rowptr + cursor
__global__ __launch_bounds__(1024) void k_scan(const int* __restrict__ hist, int* __restrict__ rowptr,
                                               int* __restrict__ cursor){
    int g = blockIdx.x;
    const int* hg = hist + g * NATOMS;
    int* rp = rowptr + g * (NATOMS + 1);
    int* cu = cursor + g * NATOMS;
    __shared__ int ssum[1024];
    int t = threadIdx.x;
    int base = t * 16;
    int v[16]; int s = 0;
    #pragma unroll
    for (int j = 0; j < 16; j++){ v[j] = hg[base + j]; s += v[j]; }
    ssum[t] = s;
    __syncthreads();
    for (int off = 1; off < 1024; off <<= 1){
        int add = (t >= off) ? ssum[t - off] : 0;
        __syncthreads();
        ssum[t] += add;
        __syncthreads();
    }
    int run = ssum[t] - s;
    #pragma unroll
    for (int j = 0; j < 16; j++){ rp[base + j] = run; cu[base + j] = run; run += v[j]; }
    if (t == 1023) rp[NATOMS] = ssum[1023];
}

// ---------------- per-edge geometry -> dst-sorted int2 meta (src|ti, tf)
__global__ __launch_bounds__(256) void k_place(const int* __restrict__ edgeA, const int* __restrict__ edgeG,
                                               const float* __restrict__ posA, const float* __restrict__ posG,
                                               int* __restrict__ cursor, int2* __restrict__ meta){
    int e = blockIdx.x * 256 + threadIdx.x;          // < 2*NEDGE
    int g = e >= NEDGE;
    int el = e - (g ? NEDGE : 0);
    const int* edge = g ? edgeG : edgeA;
    const float* pos = g ? posG : posA;
    int src = edge[el], dst = edge[NEDGE + el];
    float dx = pos[src*3+0] - pos[dst*3+0];
    float dy = pos[src*3+1] - pos[dst*3+1];
    float dz = pos[src*3+2] - pos[dst*3+2];
    float d  = sqrtf(fmaf(dx,dx, fmaf(dy,dy, fmaf(dz,dz, 1e-12f))));
    float tp = d * INV_DT;
    int   ti = (int)tp; if (ti > TK - 2) ti = TK - 2;
    float tf = tp - (float)ti;
    int p = atomicAdd(&cursor[g * NATOMS + dst], 1);
    int2 m; m.x = src | (ti << 14); m.y = __float_as_int(tf);
    meta[(size_t)g * NEDGE + p] = m;
}

// ---------------- tabulate W_i(d)*C(d) on TK knots (fp32 scratch), one wave per (interaction, knot)
__global__ __launch_bounds__(256) void k_tables(const float* __restrict__ mw1, const float* __restrict__ mb1,
                                                const float* __restrict__ mw2, const float* __restrict__ mb2,
                                                float* __restrict__ tabf){
    int wv   = blockIdx.x * 4 + (threadIdx.x >> 6);  // < NINT*TK
    int lane = threadIdx.x & 63;
    int i = wv >> 13, k = wv & (TK - 1);
    float d = (float)k * DT;
    const float step  = 10.0f / 49.0f;               // jnp.linspace(0,10,50) spacing
    const float coeff = -0.5f / (step * step);
    float u = mb1[(i << 6) + lane];
    #pragma unroll
    for (int gg = 0; gg < NGAUSS; gg++){
        float od = d - (float)gg * step;
        float ea = __expf(coeff * od * od);
        u = fmaf(ea, mw1[((i * NGAUSS + gg) << 6) + lane], u);
    }
    float t = sspf(u);
    float w = mb2[(i << 6) + lane];
    #pragma unroll
    for (int gg = 0; gg < 64; gg++){
        float tg = __shfl(t, gg, 64);
        w = fmaf(tg, mw2[(((i << 6) + gg) << 6) + lane], w);
    }
    float cc = 0.5f * (__cosf(d * 0.31415926535897932f) + 1.0f);  // cosine cutoff folded in
    tabf[((size_t)(i * TK + k) << 6) + lane] = w * cc;
}

// ---------------- pack interleaved half2 table: tab2[k][lane] = (Wk, Wk+1)
__global__ __launch_bounds__(256) void k_pack(const float* __restrict__ tabf, __half2* __restrict__ tab2){
    size_t idx = (size_t)blockIdx.x * 256 + threadIdx.x;   // < NINT*TK*64
    size_t rem = idx & ((size_t)TK * 64 - 1);              // position within one interaction
    float a = tabf[idx];
    float b = (rem < (size_t)TK * 64 - 64) ? tabf[idx + 64] : a;
    tab2[idx] = __floats2half2_rn(a, b);
}

// ---------------- x = h @ l1w (no bias), 64 nodes per block, fp16 output
__global__ __launch_bounds__(256) void k_lin1(const float* __restrict__ h, const float* __restrict__ w,
                                              __half* __restrict__ x){
    __shared__ float hs[64 * 65];
    __shared__ float ws_[64 * 64];
    int t = threadIdx.x;
    size_t base = (size_t)blockIdx.x * 64;
    #pragma unroll
    for (int j = 0; j < 16; j++){
        int idx = t + j * 256;
        hs[(idx >> 6) * 65 + (idx & 63)] = h[base * 64 + idx];
        ws_[idx] = w[idx];
    }
    __syncthreads();
    int te = t >> 4, tf4 = (t & 15) << 2;
    float acc[4][4];
    #pragma unroll
    for (int j = 0; j < 4; j++){ acc[j][0]=0.f; acc[j][1]=0.f; acc[j][2]=0.f; acc[j][3]=0.f; }
    for (int k = 0; k < 64; k++){
        float4 wv = *(const float4*)&ws_[(k << 6) + tf4];
        #pragma unroll
        for (int j = 0; j < 4; j++){
            float hv = hs[((te << 2) + j) * 65 + k];
            acc[j][0] = fmaf(hv, wv.x, acc[j][0]);
            acc[j][1] = fmaf(hv, wv.y, acc[j][1]);
            acc[j][2] = fmaf(hv, wv.z, acc[j][2]);
            acc[j][3] = fmaf(hv, wv.w, acc[j][3]);
        }
    }
    #pragma unroll
    for (int j = 0; j < 4; j++){
        union { __half2 h2[2]; float2 f2; } u;
        u.h2[0] = __floats2half2_rn(acc[j][0], acc[j][1]);
        u.h2[1] = __floats2half2_rn(acc[j][2], acc[j][3]);
        *(float2*)&x[(base + (te << 2) + j) * 64 + tf4] = u.f2;
    }
}

// ---------------- agg[dst] = sum_e x[src] * lerp(tab2) (C already folded), one wave per dst
#define PROC(M, ACC) { \
    int src_ = (M).x & 16383; int ti_ = (M).x >> 14; \
    float tf_ = __int_as_float((M).y); \
    float xv_ = __half2float(xg[(src_ << 6) + lane]); \
    float2 wf_ = __half22float2(tab2[((size_t)ti_ << 6) + lane]); \
    (ACC) = fmaf(fmaf(wf_.y - wf_.x, tf_, wf_.x), xv_, (ACC)); }

__global__ __launch_bounds__(256) void k_agg(const __half* __restrict__ x, const __half2* __restrict__ tab2,
                                             const int2* __restrict__ meta, const int* __restrict__ rowptr,
                                             float* __restrict__ agg){
    int wv   = blockIdx.x * 4 + (threadIdx.x >> 6);  // < 2*NATOMS
    int lane = threadIdx.x & 63;
    int g  = wv >= NATOMS;
    int nn = wv - (g ? NATOMS : 0);
    const int* rp = rowptr + g * (NATOMS + 1);
    int lo = rp[nn], hi = rp[nn + 1];
    const int2*  mg = meta + (size_t)g * NEDGE;
    const __half* xg = x + ((size_t)(g ? NATOMS : 0) << 6);
    float a0 = 0.f, a1 = 0.f, a2 = 0.f, a3 = 0.f;
    int e = lo;
    if (e + 4 <= hi){
        int2 m0 = mg[e], m1 = mg[e+1], m2 = mg[e+2], m3 = mg[e+3];
        for (; e + 8 <= hi; e += 4){
            int2 n0 = mg[e+4], n1 = mg[e+5], n2 = mg[e+6], n3 = mg[e+7];
            PROC(m0, a0); PROC(m1, a1); PROC(m2, a2); PROC(m3, a3);
            m0 = n0; m1 = n1; m2 = n2; m3 = n3;
        }
        PROC(m0, a0); PROC(m1, a1); PROC(m2, a2); PROC(m3, a3);
        e += 4;
    }
    for (; e < hi; e++){
        int2 m = mg[e];
        PROC(m, a0);
    }
    agg[((size_t)wv << 6) + lane] = (a0 + a1) + (a2 + a3);
}

// ---------------- fused: h += ssp(agg@w2+b2)@w3+b3 ; x = h_new @ w1_next (fp16), 64 nodes/block
__global__ __launch_bounds__(256) void k_updlin(const float* __restrict__ agg, const float* __restrict__ w2,
                                                const float* __restrict__ b2, const float* __restrict__ w3,
                                                const float* __restrict__ b3, const float* __restrict__ w1n,
                                                float* __restrict__ h, __half* __restrict__ x, int has_x){
    __shared__ float bufA[64 * 65];   // agg tile, then h_new tile
    __shared__ float bufT[64 * 65];   // ssp intermediate
    __shared__ float bufW[64 * 64];   // current weight
    int t = threadIdx.x;
    size_t base = (size_t)blockIdx.x * 64;
    #pragma unroll
    for (int j = 0; j < 16; j++){
        int idx = t + j * 256;
        bufA[(idx >> 6) * 65 + (idx & 63)] = agg[base * 64 + idx];
        bufW[idx] = w2[idx];
    }
    __syncthreads();
    int te = t >> 4, tf4 = (t & 15) << 2;
    float acc[4][4];
    // GEMM1: t = ssp(agg @ w2 + b2)
    #pragma unroll
    for (int j = 0; j < 4; j++){ acc[j][0]=0.f; acc[j][1]=0.f; acc[j][2]=0.f; acc[j][3]=0.f; }
    for (int k = 0; k < 64; k++){
        float4 wv = *(const float4*)&bufW[(k << 6) + tf4];
        #pragma unroll
        for (int j = 0; j < 4; j++){
            float av = bufA[((te << 2) + j) * 65 + k];
            acc[j][0] = fmaf(av, wv.x, acc[j][0]);
            acc[j][1] = fmaf(av, wv.y, acc[j][1]);
            acc[j][2] = fmaf(av, wv.z, acc[j][2]);
            acc[j][3] = fmaf(av, wv.w, acc[j][3]);
        }
    }
    float4 b2v = *(const float4*)&b2[tf4];
    #pragma unroll
    for (int j = 0; j < 4; j++){
        bufT[((te << 2) + j) * 65 + tf4 + 0] = sspf(acc[j][0] + b2v.x);
        bufT[((te << 2) + j) * 65 + tf4 + 1] = sspf(acc[j][1] + b2v.y);
        bufT[((te << 2) + j) * 65 + tf4 + 2] = sspf(acc[j][2] + b2v.z);
        bufT[((te << 2) + j) * 65 + tf4 + 3] = sspf(acc[j][3] + b2v.w);
    }
    __syncthreads();                      // GEMM1 reads of bufW/bufA done; bufT complete
    #pragma unroll
    for (int j = 0; j < 16; j++){
        int idx = t + j * 256;
        bufW[idx] = w3[idx];
    }
    __syncthreads();
    // GEMM2: h_new = t @ w3 + b3 + h  (write global h + bufA)
    #pragma unroll
    for (int j = 0; j < 4; j++){ acc[j][0]=0.f; acc[j][1]=0.f; acc[j][2]=0.f; acc[j][3]=0.f; }
    for (int k = 0; k < 64; k++){
        float4 wv = *(const float4*)&bufW[(k << 6) + tf4];
        #pragma unroll
        for (int j = 0; j < 4; j++){
            float tv = bufT[((te << 2) + j) * 65 + k];
            acc[j][0] = fmaf(tv, wv.x, acc[j][0]);
            acc[j][1] = fmaf(tv, wv.y, acc[j][1]);
            acc[j][2] = fmaf(tv, wv.z, acc[j][2]);
            acc[j][3] = fmaf(tv, wv.w, acc[j][3]);
        }
    }
    float4 b3v = *(const float4*)&b3[tf4];
    #pragma unroll
    for (int j = 0; j < 4; j++){
        size_t o = (base + (te << 2) + j) * 64 + tf4;
        float4 hv = *(float4*)&h[o];
        hv.x += acc[j][0] + b3v.x;
        hv.y += acc[j][1] + b3v.y;
        hv.z += acc[j][2] + b3v.z;
        hv.w += acc[j][3] + b3v.w;
        *(float4*)&h[o] = hv;
        int r = ((te << 2) + j) * 65 + tf4;
        bufA[r + 0] = hv.x; bufA[r + 1] = hv.y; bufA[r + 2] = hv.z; bufA[r + 3] = hv.w;
    }
    if (!has_x) return;
    __syncthreads();                      // bufA(h_new) complete; bufW reads done
    #pragma unroll
    for (int j = 0; j < 16; j++){
        int idx = t + j * 256;
        bufW[idx] = w1n[idx];
    }
    __syncthreads();
    // GEMM3: x = h_new @ w1_next  (fp16 out)
    #pragma unroll
    for (int j = 0; j < 4; j++){ acc[j][0]=0.f; acc[j][1]=0.f; acc[j][2]=0.f; acc[j][3]=0.f; }
    for (int k = 0; k < 64; k++){
        float4 wv = *(const float4*)&bufW[(k << 6) + tf4];
        #pragma unroll
        for (int j = 0; j < 4; j++){
            float hv = bufA[((te << 2) + j) * 65 + k];
            acc[j][0] = fmaf(hv, wv.x, acc[j][0]);
            acc[j][1] = fmaf(hv, wv.y, acc[j][1]);
            acc[j][2] = fmaf(hv, wv.z, acc[j][2]);
            acc[j][3] = fmaf(hv, wv.w, acc[j][3]);
        }
    }
    #pragma unroll
    for (int j = 0; j < 4; j++){
        union { __half2 h2[2]; float2 f2; } u;
        u.h2[0] = __floats2half2_rn(acc[j][0], acc[j][1]);
        u.h2[1] = __floats2half2_rn(acc[j][2], acc[j][3]);
        *(float2*)&x[(base + (te << 2) + j) * 64 + tf4] = u.f2;
    }
}

// ---------------- readout: eout[g][f] = sum_n h[n][f]
__global__ __launch_bounds__(256) void k_readout(const float* __restrict__ h, float* __restrict__ eout){
    int f  = threadIdx.x & 63;
    int wq = threadIdx.x >> 6;
    int nodeBase = blockIdx.x * 256 + wq * 64;
    float acc = 0.f;
    #pragma unroll 4
    for (int j = 0; j < 64; j++) acc += h[(size_t)(nodeBase + j) * 64 + f];
    int g = nodeBase >= NATOMS;
    atomicAdd(&eout[g * 64 + f], acc);
}

// ---------------- head: fc1 -> PReLU -> fc2 -> exp
__global__ __launch_bounds__(64) void k_final(const float* __restrict__ eout, const float* __restrict__ addf,
                                              const float* __restrict__ fc1w, const float* __restrict__ fc1b,
                                              const float* __restrict__ pra, const float* __restrict__ fc2w,
                                              const float* __restrict__ fc2b, float* __restrict__ out){
    int f = threadIdx.x;
    float xv = fc1b[f];
    const float inv = 1.0f / 256.0f;
    for (int k = 0; k < 64; k++)  xv = fmaf(eout[k] * inv,      fc1w[k * 64 + f],        xv);
    for (int k = 0; k < 64; k++)  xv = fmaf(eout[64 + k] * inv, fc1w[(64 + k) * 64 + f], xv);
    xv = fmaf(addf[0], fc1w[128 * 64 + f], xv);
    xv = fmaf(addf[1], fc1w[129 * 64 + f], xv);
    float a = pra[0];
    xv = (xv >= 0.f) ? xv : a * xv;
    float s = xv * fc2w[f];
    #pragma unroll
    for (int m = 32; m >= 1; m >>= 1) s += __shfl_xor(s, m, 64);
    if (f == 0) out[0] = expf(s + fc2b[0]);
}

extern "C" void kernel_launch(void* const* d_in, const int* in_sizes, int n_in,
                              void* d_out, int out_size, void* d_ws, size_t ws_size,
                              hipStream_t stream){
    const int*   zA    = (const int*)  d_in[0];
    const float* posA  = (const float*)d_in[1];
    const int*   edgeA = (const int*)  d_in[3];
    const int*   zG    = (const int*)  d_in[4];
    const float* posG  = (const float*)d_in[5];
    const int*   edgeG = (const int*)  d_in[7];
    const float* addf  = (const float*)d_in[8];
    const float* emb   = (const float*)d_in[9];
    const float* mw1   = (const float*)d_in[10];
    const float* mb1   = (const float*)d_in[11];
    const float* mw2   = (const float*)d_in[12];
    const float* mb2   = (const float*)d_in[13];
    const float* l1w   = (const float*)d_in[14];
    const float* l2w   = (const float*)d_in[15];
    const float* l2b   = (const float*)d_in[16];
    const float* l3w   = (const float*)d_in[17];
    const float* l3b   = (const float*)d_in[18];
    const float* fc1w  = (const float*)d_in[19];
    const float* fc1b  = (const float*)d_in[20];
    const float* pra   = (const float*)d_in[21];
    const float* fc2w  = (const float*)d_in[22];
    const float* fc2b  = (const float*)d_in[23];
    float* out = (float*)d_out;

    // workspace layout (~55 MB)
    char* p = (char*)d_ws;
    auto alloc = [&](size_t bytes)->char*{ char* r = p; p += (bytes + 255) & ~(size_t)255; return r; };
    float*   tabf   = (float*)  alloc((size_t)NINT * TK * 64 * 4);    // 12.6 MB fp32 scratch
    __half2* tab2   = (__half2*)alloc((size_t)NINT * TK * 64 * 4);    // 12.6 MB packed
    int2*    meta   = (int2*)   alloc((size_t)2 * NEDGE * 8);         // 8.4 MB
    int*     rowptr = (int*)    alloc((size_t)2 * (NATOMS + 1) * 4);
    int*     cursor = (int*)    alloc((size_t)2 * NATOMS * 4);
    int*     hist   = (int*)    alloc((size_t)2 * NATOMS * 4);
    float*   h      = (float*)  alloc((size_t)2 * NATOMS * 64 * 4);   // 8.4 MB
    __half*  x      = (__half*) alloc((size_t)2 * NATOMS * 64 * 2);   // 4.2 MB
    float*   agg    = (float*)  alloc((size_t)2 * NATOMS * 64 * 4);   // 8.4 MB
    float*   eout   = (float*)  alloc(128 * 4);

    hipMemsetAsync(hist, 0, (size_t)2 * NATOMS * 4, stream);
    hipMemsetAsync(eout, 0, 128 * 4, stream);

    k_embed <<<(2 * NATOMS * 64) / 256, 256, 0, stream>>>(zA, zG, emb, h);
    k_hist  <<<(2 * NEDGE) / 256,       256, 0, stream>>>(edgeA, edgeG, hist);
    k_scan  <<<2, 1024, 0, stream>>>(hist, rowptr, cursor);
    k_place <<<(2 * NEDGE) / 256,       256, 0, stream>>>(edgeA, edgeG, posA, posG, cursor, meta);
    k_tables<<<(NINT * TK) / 4,         256, 0, stream>>>(mw1, mb1, mw2, mb2, tabf);
    k_pack  <<<(NINT * TK * 64) / 256,  256, 0, stream>>>(tabf, tab2);

    k_lin1<<<(2 * NATOMS) / 64, 256, 0, stream>>>(h, l1w, x);
    for (int i = 0; i < NINT; i++){
        k_agg   <<<(2 * NATOMS) / 4,  256, 0, stream>>>(x, tab2 + (size_t)i * TK * 64, meta, rowptr, agg);
        int has_x = (i < NINT - 1);
        const float* w1n = has_x ? (l1w + (i + 1) * 4096) : l1w;
        k_updlin<<<(2 * NATOMS) / 64, 256, 0, stream>>>(agg, l2w + i * 4096, l2b + i * 64,
                                                        l3w + i * 4096, l3b + i * 64, w1n, h, x, has_x);
    }

    k_readout<<<(2 * NATOMS) / 256, 256, 0, stream>>>(h, eout);
    k_final  <<<1, 64, 0, stream>>>(eout, addf, fc1w, fc1b, pra, fc2w, fc2b, out);
}

// Round 3
// 627.471 us; speedup vs baseline: 1.3294x; 1.0883x over previous
//
#include <hip/hip_runtime.h>
#include <hip/hip_bf16.h>
#include <hip/hip_fp16.h>
#include <math.h>

#define NATOMS 16384
#define NEDGE  524288
#define NINT   6
#define NGAUSS 50
#define TK     2048
#define INV_DT 128.0f    // knots at d = k/128, range [0,16)
#define DT     (1.0f/128.0f)
#define LOG2F_ 0.69314718055994530942f

__device__ __forceinline__ float sspf(float v){
    // softplus(v) - log(2), numerically stable
    return fmaxf(v, 0.f) + log1pf(__expf(-fabsf(v))) - LOG2F_;
}

// ---------------- h = emb[z]  (rows 0..N-1 = A, N..2N-1 = G)
__global__ __launch_bounds__(256) void k_embed(const int* __restrict__ zA, const int* __restrict__ zG,
                                               const float* __restrict__ emb, float* __restrict__ h){
    int idx = blockIdx.x * 256 + threadIdx.x;        // < 2*NATOMS*64
    int n = idx >> 6, f = idx & 63;
    int z = (n < NATOMS) ? zA[n] : zG[n - NATOMS];
    h[idx] = emb[(z << 6) + f];
}

// ---------------- histogram of dst per graph
__global__ __launch_bounds__(256) void k_hist(const int* __restrict__ edgeA, const int* __restrict__ edgeG,
                                              int* __restrict__ hist){
    int e = blockIdx.x * 256 + threadIdx.x;          // < 2*NEDGE
    int g = e >= NEDGE;
    int el = e - (g ? NEDGE : 0);
    const int* edge = g ? edgeG : edgeA;
    atomicAdd(&hist[g * NATOMS + edge[NEDGE + el]], 1);
}

// ---------------- exclusive scan (one block of 1024 per graph) -> rowptr + cursor
__global__ __launch_bounds__(1024) void k_scan(const int* __restrict__ hist, int* __restrict__ rowptr,
                                               int* __restrict__ cursor){
    int g = blockIdx.x;
    const int* hg = hist + g * NATOMS;
    int* rp = rowptr + g * (NATOMS + 1);
    int* cu = cursor + g * NATOMS;
    __shared__ int ssum[1024];
    int t = threadIdx.x;
    int base = t * 16;
    int v[16]; int s = 0;
    #pragma unroll
    for (int j = 0; j < 16; j++){ v[j] = hg[base + j]; s += v[j]; }
    ssum[t] = s;
    __syncthreads();
    for (int off = 1; off < 1024; off <<= 1){
        int add = (t >= off) ? ssum[t - off] : 0;
        __syncthreads();
        ssum[t] += add;
        __syncthreads();
    }
    int run = ssum[t] - s;
    #pragma unroll
    for (int j = 0; j < 16; j++){ rp[base + j] = run; cu[base + j] = run; run += v[j]; }
    if (t == 1023) rp[NATOMS] = ssum[1023];
}

// ---------------- per-edge geometry -> dst-sorted int2 meta (src|ti<<14, tf)
__global__ __launch_bounds__(256) void k_place(const int* __restrict__ edgeA, const int* __restrict__ edgeG,
                                               const float* __restrict__ posA, const float* __restrict__ posG,
                                               int* __restrict__ cursor, int2* __restrict__ meta){
    int e = blockIdx.x * 256 + threadIdx.x;          // < 2*NEDGE
    int g = e >= NEDGE;
    int el = e - (g ? NEDGE : 0);
    const int* edge = g ? edgeG : edgeA;
    const float* pos = g ? posG : posA;
    int src = edge[el], dst = edge[NEDGE + el];
    float dx = pos[src*3+0] - pos[dst*3+0];
    float dy = pos[src*3+1] - pos[dst*3+1];
    float dz = pos[src*3+2] - pos[dst*3+2];
    float d  = sqrtf(fmaf(dx,dx, fmaf(dy,dy, fmaf(dz,dz, 1e-12f))));
    float tp = d * INV_DT;
    int   ti = (int)tp; if (ti > TK - 2) ti = TK - 2;
    float tf = tp - (float)ti;
    int p = atomicAdd(&cursor[g * NATOMS + dst], 1);
    int2 m; m.x = src | (ti << 14); m.y = __float_as_int(tf);
    meta[(size_t)g * NEDGE + p] = m;
}

// ---------------- tabulate W_i(d)*C(d) on TK knots (fp32 scratch), one wave per (interaction, knot)
__global__ __launch_bounds__(256) void k_tables(const float* __restrict__ mw1, const float* __restrict__ mb1,
                                                const float* __restrict__ mw2, const float* __restrict__ mb2,
                                                float* __restrict__ tabf){
    int wv   = blockIdx.x * 4 + (threadIdx.x >> 6);  // < NINT*TK
    int lane = threadIdx.x & 63;
    int i = wv >> 11, k = wv & (TK - 1);
    float d = (float)k * DT;
    const float step  = 10.0f / 49.0f;               // jnp.linspace(0,10,50) spacing
    const float coeff = -0.5f / (step * step);
    float u = mb1[(i << 6) + lane];
    #pragma unroll
    for (int gg = 0; gg < NGAUSS; gg++){
        float od = d - (float)gg * step;
        float ea = __expf(coeff * od * od);
        u = fmaf(ea, mw1[((i * NGAUSS + gg) << 6) + lane], u);
    }
    float t = sspf(u);
    float w = mb2[(i << 6) + lane];
    #pragma unroll
    for (int gg = 0; gg < 64; gg++){
        float tg = __shfl(t, gg, 64);
        w = fmaf(tg, mw2[(((i << 6) + gg) << 6) + lane], w);
    }
    float cc = 0.5f * (__cosf(d * 0.31415926535897932f) + 1.0f);  // cosine cutoff folded in
    tabf[((size_t)(i * TK + k) << 6) + lane] = w * cc;
}

// ---------------- pack interleaved half2 table: tab2[k][lane] = (Wk, Wk+1)
__global__ __launch_bounds__(256) void k_pack(const float* __restrict__ tabf, __half2* __restrict__ tab2){
    size_t idx = (size_t)blockIdx.x * 256 + threadIdx.x;   // < NINT*TK*64
    size_t rem = idx & ((size_t)TK * 64 - 1);              // position within one interaction
    float a = tabf[idx];
    float b = (rem < (size_t)TK * 64 - 64) ? tabf[idx + 64] : a;
    tab2[idx] = __floats2half2_rn(a, b);
}

// ---------------- x = h @ l1w (no bias), 64 nodes per block, fp16 output
__global__ __launch_bounds__(256) void k_lin1(const float* __restrict__ h, const float* __restrict__ w,
                                              __half* __restrict__ x){
    __shared__ float hs[64 * 65];
    __shared__ float ws_[64 * 64];
    int t = threadIdx.x;
    size_t base = (size_t)blockIdx.x * 64;
    #pragma unroll
    for (int j = 0; j < 16; j++){
        int idx = t + j * 256;
        hs[(idx >> 6) * 65 + (idx & 63)] = h[base * 64 + idx];
        ws_[idx] = w[idx];
    }
    __syncthreads();
    int te = t >> 4, tf4 = (t & 15) << 2;
    float acc[4][4];
    #pragma unroll
    for (int j = 0; j < 4; j++){ acc[j][0]=0.f; acc[j][1]=0.f; acc[j][2]=0.f; acc[j][3]=0.f; }
    for (int k = 0; k < 64; k++){
        float4 wv = *(const float4*)&ws_[(k << 6) + tf4];
        #pragma unroll
        for (int j = 0; j < 4; j++){
            float hv = hs[((te << 2) + j) * 65 + k];
            acc[j][0] = fmaf(hv, wv.x, acc[j][0]);
            acc[j][1] = fmaf(hv, wv.y, acc[j][1]);
            acc[j][2] = fmaf(hv, wv.z, acc[j][2]);
            acc[j][3] = fmaf(hv, wv.w, acc[j][3]);
        }
    }
    #pragma unroll
    for (int j = 0; j < 4; j++){
        union { __half2 h2[2]; float2 f2; } u;
        u.h2[0] = __floats2half2_rn(acc[j][0], acc[j][1]);
        u.h2[1] = __floats2half2_rn(acc[j][2], acc[j][3]);
        *(float2*)&x[(base + (te << 2) + j) * 64 + tf4] = u.f2;
    }
}

// ---------------- agg[dst] = sum_e x[src] * lerp(tab2), one wave per dst, XCD-partitioned by graph
#define PROC(M, ACC) { \
    int src_ = (M).x & 16383; int ti_ = (M).x >> 14; \
    float tf_ = __int_as_float((M).y); \
    float xv_ = __half2float(xg[(src_ << 6) + lane]); \
    float2 wf_ = __half22float2(tab2[((size_t)ti_ << 6) + lane]); \
    (ACC) = fmaf(fmaf(wf_.y - wf_.x, tf_, wf_.x), xv_, (ACC)); }

__global__ __launch_bounds__(256) void k_agg(const __half* __restrict__ x, const __half2* __restrict__ tab2,
                                             const int2* __restrict__ meta, const int* __restrict__ rowptr,
                                             float* __restrict__ agg){
    // XCD-aware mapping: blocks with (blockIdx&7)<4 serve graph A, else graph G.
    // Keeps each XCD's gather working set (one graph's x + table) inside its 4MB L2.
    int b    = blockIdx.x;                 // < 2*NATOMS/4 = 8192
    int xcd  = b & 7;
    int slot = b >> 3;
    int g    = xcd >> 2;
    int bi   = (slot << 2) + (xcd & 3);    // block index within graph, 0..4095
    int wq   = threadIdx.x >> 6;
    int nn   = (bi << 2) + wq;             // dst atom within graph
    int lane = threadIdx.x & 63;
    const int* rp = rowptr + g * (NATOMS + 1);
    int lo = rp[nn], hi = rp[nn + 1];
    const int2*  mg = meta + (size_t)g * NEDGE;
    const __half* xg = x + ((size_t)(g ? NATOMS : 0) << 6);
    float a0 = 0.f, a1 = 0.f, a2 = 0.f, a3 = 0.f;
    int e = lo;
    int nrem = hi - lo;
    int cnt = nrem & ~7;                   // multiple-of-8 part
    if (cnt >= 8){
        int2 m[8];
        #pragma unroll
        for (int j = 0; j < 8; j++) m[j] = mg[e + j];
        for (; e + 16 <= lo + cnt; e += 8){
            int2 n[8];
            #pragma unroll
            for (int j = 0; j < 8; j++) n[j] = mg[e + 8 + j];
            PROC(m[0], a0); PROC(m[1], a1); PROC(m[2], a2); PROC(m[3], a3);
            PROC(m[4], a0); PROC(m[5], a1); PROC(m[6], a2); PROC(m[7], a3);
            #pragma unroll
            for (int j = 0; j < 8; j++) m[j] = n[j];
        }
        PROC(m[0], a0); PROC(m[1], a1); PROC(m[2], a2); PROC(m[3], a3);
        PROC(m[4], a0); PROC(m[5], a1); PROC(m[6], a2); PROC(m[7], a3);
        e += 8;
    }
    for (; e < hi; e++){
        int2 mm = mg[e];
        PROC(mm, a0);
    }
    agg[((size_t)(g * NATOMS + nn) << 6) + lane] = (a0 + a1) + (a2 + a3);
}

// ---------------- fused: h += ssp(agg@w2+b2)@w3+b3 ; x = h_new @ w1_next (fp16), 64 nodes/block
__global__ __launch_bounds__(256) void k_updlin(const float* __restrict__ agg, const float* __restrict__ w2,
                                                const float* __restrict__ b2, const float* __restrict__ w3,
                                                const float* __restrict__ b3, const float* __restrict__ w1n,
                                                float* __restrict__ h, __half* __restrict__ x, int has_x){
    __shared__ float bufA[64 * 65];   // agg tile, then h_new tile
    __shared__ float bufT[64 * 65];   // ssp intermediate
    __shared__ float bufW[64 * 64];   // current weight
    int t = threadIdx.x;
    size_t base = (size_t)blockIdx.x * 64;
    #pragma unroll
    for (int j = 0; j < 16; j++){
        int idx = t + j * 256;
        bufA[(idx >> 6) * 65 + (idx & 63)] = agg[base * 64 + idx];
        bufW[idx] = w2[idx];
    }
    __syncthreads();
    int te = t >> 4, tf4 = (t & 15) << 2;
    float acc[4][4];
    // GEMM1: t = ssp(agg @ w2 + b2)
    #pragma unroll
    for (int j = 0; j < 4; j++){ acc[j][0]=0.f; acc[j][1]=0.f; acc[j][2]=0.f; acc[j][3]=0.f; }
    for (int k = 0; k < 64; k++){
        float4 wv = *(const float4*)&bufW[(k << 6) + tf4];
        #pragma unroll
        for (int j = 0; j < 4; j++){
            float av = bufA[((te << 2) + j) * 65 + k];
            acc[j][0] = fmaf(av, wv.x, acc[j][0]);
            acc[j][1] = fmaf(av, wv.y, acc[j][1]);
            acc[j][2] = fmaf(av, wv.z, acc[j][2]);
            acc[j][3] = fmaf(av, wv.w, acc[j][3]);
        }
    }
    float4 b2v = *(const float4*)&b2[tf4];
    #pragma unroll
    for (int j = 0; j < 4; j++){
        bufT[((te << 2) + j) * 65 + tf4 + 0] = sspf(acc[j][0] + b2v.x);
        bufT[((te << 2) + j) * 65 + tf4 + 1] = sspf(acc[j][1] + b2v.y);
        bufT[((te << 2) + j) * 65 + tf4 + 2] = sspf(acc[j][2] + b2v.z);
        bufT[((te << 2) + j) * 65 + tf4 + 3] = sspf(acc[j][3] + b2v.w);
    }
    __syncthreads();
    #pragma unroll
    for (int j = 0; j < 16; j++){
        int idx = t + j * 256;
        bufW[idx] = w3[idx];
    }
    __syncthreads();
    // GEMM2: h_new = t @ w3 + b3 + h  (write global h + bufA)
    #pragma unroll
    for (int j = 0; j < 4; j++){ acc[j][0]=0.f; acc[j][1]=0.f; acc[j][2]=0.f; acc[j][3]=0.f; }
    for (int k = 0; k < 64; k++){
        float4 wv = *(const float4*)&bufW[(k << 6) + tf4];
        #pragma unroll
        for (int j = 0; j < 4; j++){
            float tv = bufT[((te << 2) + j) * 65 + k];
            acc[j][0] = fmaf(tv, wv.x, acc[j][0]);
            acc[j][1] = fmaf(tv, wv.y, acc[j][1]);
            acc[j][2] = fmaf(tv, wv.z, acc[j][2]);
            acc[j][3] = fmaf(tv, wv.w, acc[j][3]);
        }
    }
    float4 b3v = *(const float4*)&b3[tf4];
    #pragma unroll
    for (int j = 0; j < 4; j++){
        size_t o = (base + (te << 2) + j) * 64 + tf4;
        float4 hv = *(float4*)&h[o];
        hv.x += acc[j][0] + b3v.x;
        hv.y += acc[j][1] + b3v.y;
        hv.z += acc[j][2] + b3v.z;
        hv.w += acc[j][3] + b3v.w;
        *(float4*)&h[o] = hv;
        int r = ((te << 2) + j) * 65 + tf4;
        bufA[r + 0] = hv.x; bufA[r + 1] = hv.y; bufA[r + 2] = hv.z; bufA[r + 3] = hv.w;
    }
    if (!has_x) return;
    __syncthreads();
    #pragma unroll
    for (int j = 0; j < 16; j++){
        int idx = t + j * 256;
        bufW[idx] = w1n[idx];
    }
    __syncthreads();
    // GEMM3: x = h_new @ w1_next  (fp16 out)
    #pragma unroll
    for (int j = 0; j < 4; j++){ acc[j][0]=0.f; acc[j][1]=0.f; acc[j][2]=0.f; acc[j][3]=0.f; }
    for (int k = 0; k < 64; k++){
        float4 wv = *(const float4*)&bufW[(k << 6) + tf4];
        #pragma unroll
        for (int j = 0; j < 4; j++){
            float hv = bufA[((te << 2) + j) * 65 + k];
            acc[j][0] = fmaf(hv, wv.x, acc[j][0]);
            acc[j][1] = fmaf(hv, wv.y, acc[j][1]);
            acc[j][2] = fmaf(hv, wv.z, acc[j][2]);
            acc[j][3] = fmaf(hv, wv.w, acc[j][3]);
        }
    }
    #pragma unroll
    for (int j = 0; j < 4; j++){
        union { __half2 h2[2]; float2 f2; } u;
        u.h2[0] = __floats2half2_rn(acc[j][0], acc[j][1]);
        u.h2[1] = __floats2half2_rn(acc[j][2], acc[j][3]);
        *(float2*)&x[(base + (te << 2) + j) * 64 + tf4] = u.f2;
    }
}

// ---------------- readout: eout[g][f] = sum_n h[n][f]
__global__ __launch_bounds__(256) void k_readout(const float* __restrict__ h, float* __restrict__ eout){
    int f  = threadIdx.x & 63;
    int wq = threadIdx.x >> 6;
    int nodeBase = blockIdx.x * 256 + wq * 64;
    float acc = 0.f;
    #pragma unroll 4
    for (int j = 0; j < 64; j++) acc += h[(size_t)(nodeBase + j) * 64 + f];
    int g = nodeBase >= NATOMS;
    atomicAdd(&eout[g * 64 + f], acc);
}

// ---------------- head: fc1 -> PReLU -> fc2 -> exp
__global__ __launch_bounds__(64) void k_final(const float* __restrict__ eout, const float* __restrict__ addf,
                                              const float* __restrict__ fc1w, const float* __restrict__ fc1b,
                                              const float* __restrict__ pra, const float* __restrict__ fc2w,
                                              const float* __restrict__ fc2b, float* __restrict__ out){
    int f = threadIdx.x;
    float xv = fc1b[f];
    const float inv = 1.0f / 256.0f;
    for (int k = 0; k < 64; k++)  xv = fmaf(eout[k] * inv,      fc1w[k * 64 + f],        xv);
    for (int k = 0; k < 64; k++)  xv = fmaf(eout[64 + k] * inv, fc1w[(64 + k) * 64 + f], xv);
    xv = fmaf(addf[0], fc1w[128 * 64 + f], xv);
    xv = fmaf(addf[1], fc1w[129 * 64 + f], xv);
    float a = pra[0];
    xv = (xv >= 0.f) ? xv : a * xv;
    float s = xv * fc2w[f];
    #pragma unroll
    for (int m = 32; m >= 1; m >>= 1) s += __shfl_xor(s, m, 64);
    if (f == 0) out[0] = expf(s + fc2b[0]);
}

extern "C" void kernel_launch(void* const* d_in, const int* in_sizes, int n_in,
                              void* d_out, int out_size, void* d_ws, size_t ws_size,
                              hipStream_t stream){
    const int*   zA    = (const int*)  d_in[0];
    const float* posA  = (const float*)d_in[1];
    const int*   edgeA = (const int*)  d_in[3];
    const int*   zG    = (const int*)  d_in[4];
    const float* posG  = (const float*)d_in[5];
    const int*   edgeG = (const int*)  d_in[7];
    const float* addf  = (const float*)d_in[8];
    const float* emb   = (const float*)d_in[9];
    const float* mw1   = (const float*)d_in[10];
    const float* mb1   = (const float*)d_in[11];
    const float* mw2   = (const float*)d_in[12];
    const float* mb2   = (const float*)d_in[13];
    const float* l1w   = (const float*)d_in[14];
    const float* l2w   = (const float*)d_in[15];
    const float* l2b   = (const float*)d_in[16];
    const float* l3w   = (const float*)d_in[17];
    const float* l3b   = (const float*)d_in[18];
    const float* fc1w  = (const float*)d_in[19];
    const float* fc1b  = (const float*)d_in[20];
    const float* pra   = (const float*)d_in[21];
    const float* fc2w  = (const float*)d_in[22];
    const float* fc2b  = (const float*)d_in[23];
    float* out = (float*)d_out;

    // workspace layout (~40 MB)
    char* p = (char*)d_ws;
    auto alloc = [&](size_t bytes)->char*{ char* r = p; p += (bytes + 255) & ~(size_t)255; return r; };
    float*   tabf   = (float*)  alloc((size_t)NINT * TK * 64 * 4);    // 3.1 MB fp32 scratch
    __half2* tab2   = (__half2*)alloc((size_t)NINT * TK * 64 * 4);    // 3.1 MB packed
    int2*    meta   = (int2*)   alloc((size_t)2 * NEDGE * 8);         // 8.4 MB
    int*     rowptr = (int*)    alloc((size_t)2 * (NATOMS + 1) * 4);
    int*     cursor = (int*)    alloc((size_t)2 * NATOMS * 4);
    int*     hist   = (int*)    alloc((size_t)2 * NATOMS * 4);
    float*   h      = (float*)  alloc((size_t)2 * NATOMS * 64 * 4);   // 8.4 MB
    __half*  x      = (__half*) alloc((size_t)2 * NATOMS * 64 * 2);   // 4.2 MB
    float*   agg    = (float*)  alloc((size_t)2 * NATOMS * 64 * 4);   // 8.4 MB
    float*   eout   = (float*)  alloc(128 * 4);

    hipMemsetAsync(hist, 0, (size_t)2 * NATOMS * 4, stream);
    hipMemsetAsync(eout, 0, 128 * 4, stream);

    k_embed <<<(2 * NATOMS * 64) / 256, 256, 0, stream>>>(zA, zG, emb, h);
    k_hist  <<<(2 * NEDGE) / 256,       256, 0, stream>>>(edgeA, edgeG, hist);
    k_scan  <<<2, 1024, 0, stream>>>(hist, rowptr, cursor);
    k_place <<<(2 * NEDGE) / 256,       256, 0, stream>>>(edgeA, edgeG, posA, posG, cursor, meta);
    k_tables<<<(NINT * TK) / 4,         256, 0, stream>>>(mw1, mb1, mw2, mb2, tabf);
    k_pack  <<<(NINT * TK * 64) / 256,  256, 0, stream>>>(tabf, tab2);

    k_lin1<<<(2 * NATOMS) / 64, 256, 0, stream>>>(h, l1w, x);
    for (int i = 0; i < NINT; i++){
        k_agg   <<<(2 * NATOMS) / 4,  256, 0, stream>>>(x, tab2 + (size_t)i * TK * 64, meta, rowptr, agg);
        int has_x = (i < NINT - 1);
        const float* w1n = has_x ? (l1w + (i + 1) * 4096) : l1w;
        k_updlin<<<(2 * NATOMS) / 64, 256, 0, stream>>>(agg, l2w + i * 4096, l2b + i * 64,
                                                        l3w + i * 4096, l3b + i * 64, w1n, h, x, has_x);
    }

    k_readout<<<(2 * NATOMS) / 256, 256, 0, stream>>>(h, eout);
    k_final  <<<1, 64, 0, stream>>>(eout, addf, fc1w, fc1b, pra, fc2w, fc2b, out);
}

// Round 4
// 607.919 us; speedup vs baseline: 1.3722x; 1.0322x over previous
//
#include <hip/hip_runtime.h>
#include <hip/hip_bf16.h>
#include <hip/hip_fp16.h>
#include <math.h>

#define NATOMS 16384
#define NEDGE  524288
#define NINT   6
#define NGAUSS 50
#define TK     2048
#define INV_DT 128.0f    // knots at d = k/128, range [0,16)
#define DT     (1.0f/128.0f)
#define LOG2F_ 0.69314718055994530942f

__device__ __forceinline__ float sspf(float v){
    // softplus(v) - log(2), numerically stable
    return fmaxf(v, 0.f) + log1pf(__expf(-fabsf(v))) - LOG2F_;
}

// ---------------- h = emb[z]  (rows 0..N-1 = A, N..2N-1 = G)
__global__ __launch_bounds__(256) void k_embed(const int* __restrict__ zA, const int* __restrict__ zG,
                                               const float* __restrict__ emb, float* __restrict__ h){
    int idx = blockIdx.x * 256 + threadIdx.x;        // < 2*NATOMS*64
    int n = idx >> 6, f = idx & 63;
    int z = (n < NATOMS) ? zA[n] : zG[n - NATOMS];
    h[idx] = emb[(z << 6) + f];
}

// ---------------- histogram of dst per graph
__global__ __launch_bounds__(256) void k_hist(const int* __restrict__ edgeA, const int* __restrict__ edgeG,
                                              int* __restrict__ hist){
    int e = blockIdx.x * 256 + threadIdx.x;          // < 2*NEDGE
    int g = e >= NEDGE;
    int el = e - (g ? NEDGE : 0);
    const int* edge = g ? edgeG : edgeA;
    atomicAdd(&hist[g * NATOMS + edge[NEDGE + el]], 1);
}

// ---------------- exclusive scan (one block of 1024 per graph) -> rowptr + cursor
__global__ __launch_bounds__(1024) void k_scan(const int* __restrict__ hist, int* __restrict__ rowptr,
                                               int* __restrict__ cursor){
    int g = blockIdx.x;
    const int* hg = hist + g * NATOMS;
    int* rp = rowptr + g * (NATOMS + 1);
    int* cu = cursor + g * NATOMS;
    __shared__ int ssum[1024];
    int t = threadIdx.x;
    int base = t * 16;
    int v[16]; int s = 0;
    #pragma unroll
    for (int j = 0; j < 16; j++){ v[j] = hg[base + j]; s += v[j]; }
    ssum[t] = s;
    __syncthreads();
    for (int off = 1; off < 1024; off <<= 1){
        int add = (t >= off) ? ssum[t - off] : 0;
        __syncthreads();
        ssum[t] += add;
        __syncthreads();
    }
    int run = ssum[t] - s;
    #pragma unroll
    for (int j = 0; j < 16; j++){ rp[base + j] = run; cu[base + j] = run; run += v[j]; }
    if (t == 1023) rp[NATOMS] = ssum[1023];
}

// ---------------- per-edge geometry -> dst-sorted 4B meta (src:14 | ti:11 | tq:7)
__global__ __launch_bounds__(256) void k_place(const int* __restrict__ edgeA, const int* __restrict__ edgeG,
                                               const float* __restrict__ posA, const float* __restrict__ posG,
                                               int* __restrict__ cursor, unsigned int* __restrict__ meta){
    int e = blockIdx.x * 256 + threadIdx.x;          // < 2*NEDGE
    int g = e >= NEDGE;
    int el = e - (g ? NEDGE : 0);
    const int* edge = g ? edgeG : edgeA;
    const float* pos = g ? posG : posA;
    int src = edge[el], dst = edge[NEDGE + el];
    float dx = pos[src*3+0] - pos[dst*3+0];
    float dy = pos[src*3+1] - pos[dst*3+1];
    float dz = pos[src*3+2] - pos[dst*3+2];
    float d  = sqrtf(fmaf(dx,dx, fmaf(dy,dy, fmaf(dz,dz, 1e-12f))));
    float tp = d * INV_DT;
    int   ti = (int)tp; if (ti > TK - 2) ti = TK - 2;
    float tf = tp - (float)ti;
    int   tq = (int)(tf * 128.0f + 0.5f); if (tq > 127) tq = 127;
    int p = atomicAdd(&cursor[g * NATOMS + dst], 1);
    meta[(size_t)g * NEDGE + p] = (unsigned int)src | ((unsigned int)ti << 14) | ((unsigned int)tq << 25);
}

// ---------------- tabulate W_i(d)*C(d) on TK knots (fp32 scratch), one wave per (interaction, knot)
__global__ __launch_bounds__(256) void k_tables(const float* __restrict__ mw1, const float* __restrict__ mb1,
                                                const float* __restrict__ mw2, const float* __restrict__ mb2,
                                                float* __restrict__ tabf){
    int wv   = blockIdx.x * 4 + (threadIdx.x >> 6);  // < NINT*TK
    int lane = threadIdx.x & 63;
    int i = wv >> 11, k = wv & (TK - 1);
    float d = (float)k * DT;
    const float step  = 10.0f / 49.0f;               // jnp.linspace(0,10,50) spacing
    const float coeff = -0.5f / (step * step);
    float u = mb1[(i << 6) + lane];
    #pragma unroll
    for (int gg = 0; gg < NGAUSS; gg++){
        float od = d - (float)gg * step;
        float ea = __expf(coeff * od * od);
        u = fmaf(ea, mw1[((i * NGAUSS + gg) << 6) + lane], u);
    }
    float t = sspf(u);
    float w = mb2[(i << 6) + lane];
    #pragma unroll
    for (int gg = 0; gg < 64; gg++){
        float tg = __shfl(t, gg, 64);
        w = fmaf(tg, mw2[(((i << 6) + gg) << 6) + lane], w);
    }
    float cc = 0.5f * (__cosf(d * 0.31415926535897932f) + 1.0f);  // cosine cutoff folded in
    tabf[((size_t)(i * TK + k) << 6) + lane] = w * cc;
}

// ---------------- pack interleaved half2 table: tab2[k][lane] = (Wk, Wk+1)
__global__ __launch_bounds__(256) void k_pack(const float* __restrict__ tabf, __half2* __restrict__ tab2){
    size_t idx = (size_t)blockIdx.x * 256 + threadIdx.x;   // < NINT*TK*64
    size_t rem = idx & ((size_t)TK * 64 - 1);              // position within one interaction
    float a = tabf[idx];
    float b = (rem < (size_t)TK * 64 - 64) ? tabf[idx + 64] : a;
    tab2[idx] = __floats2half2_rn(a, b);
}

// ---------------- x = h @ l1w (no bias), 64 nodes per block, fp16 output
__global__ __launch_bounds__(256) void k_lin1(const float* __restrict__ h, const float* __restrict__ w,
                                              __half* __restrict__ x){
    __shared__ float hs[64 * 65];
    __shared__ float ws_[64 * 64];
    int t = threadIdx.x;
    size_t base = (size_t)blockIdx.x * 64;
    #pragma unroll
    for (int j = 0; j < 16; j++){
        int idx = t + j * 256;
        hs[(idx >> 6) * 65 + (idx & 63)] = h[base * 64 + idx];
        ws_[idx] = w[idx];
    }
    __syncthreads();
    int te = t >> 4, tf4 = (t & 15) << 2;
    float acc[4][4];
    #pragma unroll
    for (int j = 0; j < 4; j++){ acc[j][0]=0.f; acc[j][1]=0.f; acc[j][2]=0.f; acc[j][3]=0.f; }
    for (int k = 0; k < 64; k++){
        float4 wv = *(const float4*)&ws_[(k << 6) + tf4];
        #pragma unroll
        for (int j = 0; j < 4; j++){
            float hv = hs[((te << 2) + j) * 65 + k];
            acc[j][0] = fmaf(hv, wv.x, acc[j][0]);
            acc[j][1] = fmaf(hv, wv.y, acc[j][1]);
            acc[j][2] = fmaf(hv, wv.z, acc[j][2]);
            acc[j][3] = fmaf(hv, wv.w, acc[j][3]);
        }
    }
    #pragma unroll
    for (int j = 0; j < 4; j++){
        union { __half2 h2[2]; float2 f2; } u;
        u.h2[0] = __floats2half2_rn(acc[j][0], acc[j][1]);
        u.h2[1] = __floats2half2_rn(acc[j][2], acc[j][3]);
        *(float2*)&x[(base + (te << 2) + j) * 64 + tf4] = u.f2;
    }
}

// ---------------- agg[dst] = sum_e x[src] * lerp(tab2), one wave per dst, XCD-partitioned by graph
#define PROC(M, ACC) { \
    unsigned int mm_ = (M); \
    int src_ = (int)(mm_ & 16383u); int ti_ = (int)((mm_ >> 14) & 2047u); \
    float tf_ = (float)(mm_ >> 25) * 0.0078125f; \
    float xv_ = __half2float(xg[(src_ << 6) + lane]); \
    float2 wf_ = __half22float2(tab2[((size_t)ti_ << 6) + lane]); \
    (ACC) = fmaf(fmaf(wf_.y - wf_.x, tf_, wf_.x), xv_, (ACC)); }

__global__ __launch_bounds__(256) void k_agg(const __half* __restrict__ x, const __half2* __restrict__ tab2,
                                             const unsigned int* __restrict__ meta, const int* __restrict__ rowptr,
                                             float* __restrict__ agg){
    // XCD-aware mapping: blocks with (blockIdx&7)<4 serve graph A, else graph G.
    int b    = blockIdx.x;                 // < 2*NATOMS/4 = 8192
    int xcd  = b & 7;
    int slot = b >> 3;
    int g    = xcd >> 2;
    int bi   = (slot << 2) + (xcd & 3);    // block index within graph, 0..4095
    int wq   = threadIdx.x >> 6;
    int nn   = (bi << 2) + wq;             // dst atom within graph
    int lane = threadIdx.x & 63;
    const int* rp = rowptr + g * (NATOMS + 1);
    int lo = rp[nn], hi = rp[nn + 1];
    const unsigned int* mg = meta + (size_t)g * NEDGE;
    const __half* xg = x + ((size_t)(g ? NATOMS : 0) << 6);
    float a0 = 0.f, a1 = 0.f, a2 = 0.f, a3 = 0.f;
    int e = lo;
    // 16-deep double-buffered main loop
    if (e + 16 <= hi){
        unsigned int m[16];
        #pragma unroll
        for (int j = 0; j < 16; j++) m[j] = mg[e + j];
        for (; e + 32 <= hi; e += 16){
            unsigned int n[16];
            #pragma unroll
            for (int j = 0; j < 16; j++) n[j] = mg[e + 16 + j];
            #pragma unroll
            for (int j = 0; j < 16; j += 4){
                PROC(m[j+0], a0); PROC(m[j+1], a1); PROC(m[j+2], a2); PROC(m[j+3], a3);
            }
            #pragma unroll
            for (int j = 0; j < 16; j++) m[j] = n[j];
        }
        #pragma unroll
        for (int j = 0; j < 16; j += 4){
            PROC(m[j+0], a0); PROC(m[j+1], a1); PROC(m[j+2], a2); PROC(m[j+3], a3);
        }
        e += 16;
    }
    // 4-chunks
    for (; e + 4 <= hi; e += 4){
        unsigned int m0 = mg[e], m1 = mg[e+1], m2 = mg[e+2], m3 = mg[e+3];
        PROC(m0, a0); PROC(m1, a1); PROC(m2, a2); PROC(m3, a3);
    }
    // scalar tail
    for (; e < hi; e++){
        unsigned int mm = mg[e];
        PROC(mm, a0);
    }
    agg[((size_t)(g * NATOMS + nn) << 6) + lane] = (a0 + a1) + (a2 + a3);
}

// ---------------- fused: h += ssp(agg@w2+b2)@w3+b3 ; x = h_new @ w1_next (fp16), 64 nodes/block
__global__ __launch_bounds__(256) void k_updlin(const float* __restrict__ agg, const float* __restrict__ w2,
                                                const float* __restrict__ b2, const float* __restrict__ w3,
                                                const float* __restrict__ b3, const float* __restrict__ w1n,
                                                float* __restrict__ h, __half* __restrict__ x, int has_x){
    __shared__ float bufA[64 * 65];   // agg tile, then h_new tile
    __shared__ float bufT[64 * 65];   // ssp intermediate
    __shared__ float bufW[64 * 64];   // current weight
    int t = threadIdx.x;
    size_t base = (size_t)blockIdx.x * 64;
    #pragma unroll
    for (int j = 0; j < 16; j++){
        int idx = t + j * 256;
        bufA[(idx >> 6) * 65 + (idx & 63)] = agg[base * 64 + idx];
        bufW[idx] = w2[idx];
    }
    __syncthreads();
    int te = t >> 4, tf4 = (t & 15) << 2;
    float acc[4][4];
    // GEMM1: t = ssp(agg @ w2 + b2)
    #pragma unroll
    for (int j = 0; j < 4; j++){ acc[j][0]=0.f; acc[j][1]=0.f; acc[j][2]=0.f; acc[j][3]=0.f; }
    for (int k = 0; k < 64; k++){
        float4 wv = *(const float4*)&bufW[(k << 6) + tf4];
        #pragma unroll
        for (int j = 0; j < 4; j++){
            float av = bufA[((te << 2) + j) * 65 + k];
            acc[j][0] = fmaf(av, wv.x, acc[j][0]);
            acc[j][1] = fmaf(av, wv.y, acc[j][1]);
            acc[j][2] = fmaf(av, wv.z, acc[j][2]);
            acc[j][3] = fmaf(av, wv.w, acc[j][3]);
        }
    }
    float4 b2v = *(const float4*)&b2[tf4];
    #pragma unroll
    for (int j = 0; j < 4; j++){
        bufT[((te << 2) + j) * 65 + tf4 + 0] = sspf(acc[j][0] + b2v.x);
        bufT[((te << 2) + j) * 65 + tf4 + 1] = sspf(acc[j][1] + b2v.y);
        bufT[((te << 2) + j) * 65 + tf4 + 2] = sspf(acc[j][2] + b2v.z);
        bufT[((te << 2) + j) * 65 + tf4 + 3] = sspf(acc[j][3] + b2v.w);
    }
    __syncthreads();
    #pragma unroll
    for (int j = 0; j < 16; j++){
        int idx = t + j * 256;
        bufW[idx] = w3[idx];
    }
    __syncthreads();
    // GEMM2: h_new = t @ w3 + b3 + h  (write global h + bufA)
    #pragma unroll
    for (int j = 0; j < 4; j++){ acc[j][0]=0.f; acc[j][1]=0.f; acc[j][2]=0.f; acc[j][3]=0.f; }
    for (int k = 0; k < 64; k++){
        float4 wv = *(const float4*)&bufW[(k << 6) + tf4];
        #pragma unroll
        for (int j = 0; j < 4; j++){
            float tv = bufT[((te << 2) + j) * 65 + k];
            acc[j][0] = fmaf(tv, wv.x, acc[j][0]);
            acc[j][1] = fmaf(tv, wv.y, acc[j][1]);
            acc[j][2] = fmaf(tv, wv.z, acc[j][2]);
            acc[j][3] = fmaf(tv, wv.w, acc[j][3]);
        }
    }
    float4 b3v = *(const float4*)&b3[tf4];
    #pragma unroll
    for (int j = 0; j < 4; j++){
        size_t o = (base + (te << 2) + j) * 64 + tf4;
        float4 hv = *(float4*)&h[o];
        hv.x += acc[j][0] + b3v.x;
        hv.y += acc[j][1] + b3v.y;
        hv.z += acc[j][2] + b3v.z;
        hv.w += acc[j][3] + b3v.w;
        *(float4*)&h[o] = hv;
        int r = ((te << 2) + j) * 65 + tf4;
        bufA[r + 0] = hv.x; bufA[r + 1] = hv.y; bufA[r + 2] = hv.z; bufA[r + 3] = hv.w;
    }
    if (!has_x) return;
    __syncthreads();
    #pragma unroll
    for (int j = 0; j < 16; j++){
        int idx = t + j * 256;
        bufW[idx] = w1n[idx];
    }
    __syncthreads();
    // GEMM3: x = h_new @ w1_next  (fp16 out)
    #pragma unroll
    for (int j = 0; j < 4; j++){ acc[j][0]=0.f; acc[j][1]=0.f; acc[j][2]=0.f; acc[j][3]=0.f; }
    for (int k = 0; k < 64; k++){
        float4 wv = *(const float4*)&bufW[(k << 6) + tf4];
        #pragma unroll
        for (int j = 0; j < 4; j++){
            float hv = bufA[((te << 2) + j) * 65 + k];
            acc[j][0] = fmaf(hv, wv.x, acc[j][0]);
            acc[j][1] = fmaf(hv, wv.y, acc[j][1]);
            acc[j][2] = fmaf(hv, wv.z, acc[j][2]);
            acc[j][3] = fmaf(hv, wv.w, acc[j][3]);
        }
    }
    #pragma unroll
    for (int j = 0; j < 4; j++){
        union { __half2 h2[2]; float2 f2; } u;
        u.h2[0] = __floats2half2_rn(acc[j][0], acc[j][1]);
        u.h2[1] = __floats2half2_rn(acc[j][2], acc[j][3]);
        *(float2*)&x[(base + (te << 2) + j) * 64 + tf4] = u.f2;
    }
}

// ---------------- readout: eout[g][f] = sum_n h[n][f]
__global__ __launch_bounds__(256) void k_readout(const float* __restrict__ h, float* __restrict__ eout){
    int f  = threadIdx.x & 63;
    int wq = threadIdx.x >> 6;
    int nodeBase = blockIdx.x * 256 + wq * 64;
    float acc = 0.f;
    #pragma unroll 4
    for (int j = 0; j < 64; j++) acc += h[(size_t)(nodeBase + j) * 64 + f];
    int g = nodeBase >= NATOMS;
    atomicAdd(&eout[g * 64 + f], acc);
}

// ---------------- head: fc1 -> PReLU -> fc2 -> exp
__global__ __launch_bounds__(64) void k_final(const float* __restrict__ eout, const float* __restrict__ addf,
                                              const float* __restrict__ fc1w, const float* __restrict__ fc1b,
                                              const float* __restrict__ pra, const float* __restrict__ fc2w,
                                              const float* __restrict__ fc2b, float* __restrict__ out){
    int f = threadIdx.x;
    float xv = fc1b[f];
    const float inv = 1.0f / 256.0f;
    for (int k = 0; k < 64; k++)  xv = fmaf(eout[k] * inv,      fc1w[k * 64 + f],        xv);
    for (int k = 0; k < 64; k++)  xv = fmaf(eout[64 + k] * inv, fc1w[(64 + k) * 64 + f], xv);
    xv = fmaf(addf[0], fc1w[128 * 64 + f], xv);
    xv = fmaf(addf[1], fc1w[129 * 64 + f], xv);
    float a = pra[0];
    xv = (xv >= 0.f) ? xv : a * xv;
    float s = xv * fc2w[f];
    #pragma unroll
    for (int m = 32; m >= 1; m >>= 1) s += __shfl_xor(s, m, 64);
    if (f == 0) out[0] = expf(s + fc2b[0]);
}

extern "C" void kernel_launch(void* const* d_in, const int* in_sizes, int n_in,
                              void* d_out, int out_size, void* d_ws, size_t ws_size,
                              hipStream_t stream){
    const int*   zA    = (const int*)  d_in[0];
    const float* posA  = (const float*)d_in[1];
    const int*   edgeA = (const int*)  d_in[3];
    const int*   zG    = (const int*)  d_in[4];
    const float* posG  = (const float*)d_in[5];
    const int*   edgeG = (const int*)  d_in[7];
    const float* addf  = (const float*)d_in[8];
    const float* emb   = (const float*)d_in[9];
    const float* mw1   = (const float*)d_in[10];
    const float* mb1   = (const float*)d_in[11];
    const float* mw2   = (const float*)d_in[12];
    const float* mb2   = (const float*)d_in[13];
    const float* l1w   = (const float*)d_in[14];
    const float* l2w   = (const float*)d_in[15];
    const float* l2b   = (const float*)d_in[16];
    const float* l3w   = (const float*)d_in[17];
    const float* l3b   = (const float*)d_in[18];
    const float* fc1w  = (const float*)d_in[19];
    const float* fc1b  = (const float*)d_in[20];
    const float* pra   = (const float*)d_in[21];
    const float* fc2w  = (const float*)d_in[22];
    const float* fc2b  = (const float*)d_in[23];
    float* out = (float*)d_out;

    // workspace layout (~36 MB)
    char* p = (char*)d_ws;
    auto alloc = [&](size_t bytes)->char*{ char* r = p; p += (bytes + 255) & ~(size_t)255; return r; };
    float*        tabf   = (float*)       alloc((size_t)NINT * TK * 64 * 4);   // 3.1 MB fp32 scratch
    __half2*      tab2   = (__half2*)     alloc((size_t)NINT * TK * 64 * 4);   // 3.1 MB packed
    unsigned int* meta   = (unsigned int*)alloc((size_t)2 * NEDGE * 4);        // 4.2 MB
    int*          rowptr = (int*)         alloc((size_t)2 * (NATOMS + 1) * 4);
    int*          cursor = (int*)         alloc((size_t)2 * NATOMS * 4);
    int*          hist   = (int*)         alloc((size_t)2 * NATOMS * 4);
    float*        h      = (float*)       alloc((size_t)2 * NATOMS * 64 * 4);  // 8.4 MB
    __half*       x      = (__half*)      alloc((size_t)2 * NATOMS * 64 * 2);  // 4.2 MB
    float*        agg    = (float*)       alloc((size_t)2 * NATOMS * 64 * 4);  // 8.4 MB
    float*        eout   = (float*)       alloc(128 * 4);

    hipMemsetAsync(hist, 0, (size_t)2 * NATOMS * 4, stream);
    hipMemsetAsync(eout, 0, 128 * 4, stream);

    k_embed <<<(2 * NATOMS * 64) / 256, 256, 0, stream>>>(zA, zG, emb, h);
    k_hist  <<<(2 * NEDGE) / 256,       256, 0, stream>>>(edgeA, edgeG, hist);
    k_scan  <<<2, 1024, 0, stream>>>(hist, rowptr, cursor);
    k_place <<<(2 * NEDGE) / 256,       256, 0, stream>>>(edgeA, edgeG, posA, posG, cursor, meta);
    k_tables<<<(NINT * TK) / 4,         256, 0, stream>>>(mw1, mb1, mw2, mb2, tabf);
    k_pack  <<<(NINT * TK * 64) / 256,  256, 0, stream>>>(tabf, tab2);

    k_lin1<<<(2 * NATOMS) / 64, 256, 0, stream>>>(h, l1w, x);
    for (int i = 0; i < NINT; i++){
        k_agg   <<<(2 * NATOMS) / 4,  256, 0, stream>>>(x, tab2 + (size_t)i * TK * 64, meta, rowptr, agg);
        int has_x = (i < NINT - 1);
        const float* w1n = has_x ? (l1w + (i + 1) * 4096) : l1w;
        k_updlin<<<(2 * NATOMS) / 64, 256, 0, stream>>>(agg, l2w + i * 4096, l2b + i * 64,
                                                        l3w + i * 4096, l3b + i * 64, w1n, h, x, has_x);
    }

    k_readout<<<(2 * NATOMS) / 256, 256, 0, stream>>>(h, eout);
    k_final  <<<1, 64, 0, stream>>>(eout, addf, fc1w, fc1b, pra, fc2w, fc2b, out);
}